// Round 2
// baseline (225.931 us; speedup 1.0000x reference)
//
#include <hip/hip_runtime.h>

// PixelShuffle1d: x (8, 256, 16384) f32 -> out (8, 64, 65536) f32, upscale=4.
//   out4[bc*16384 + l] = { row0[l], row1[l], row2[l], row3[l] }   (float4 quads)
// where row_j = x + bc*65536 + j*16384.
//
// Cross-lane 4x4 transpose: lanes are grouped in 4s. Lane p of a group loads
// one float4 from source row p (per-instruction: 4 contiguous 256B runs per
// wave), the group transposes via 3 __shfl rounds, then every lane stores one
// float4 at out4[tid] (per-instruction: contiguous 1 KiB per wave).
//
// Shuffle algebra: v_p = row_p[l0..l0+3]; lane p wants w[j] = v_j[p].
// Round r: publish v[(p-r)&3], read from group-lane (p+r)&3 -> got v_j[p],
// j = (p+r)&3.  (r=0 is the identity.)

constexpr int L  = 16384;       // input inner length (floats)
constexpr int LQ = L / 4;       // 4096 float4 chunks per row
constexpr int TOTAL = 8 * 64 * L;   // 2^23 output quads == total threads

__device__ __forceinline__ float sel4(const float4& v, int i) {
    float r = v.x;
    r = (i == 1) ? v.y : r;
    r = (i == 2) ? v.z : r;
    r = (i == 3) ? v.w : r;
    return r;
}

__device__ __forceinline__ float selg(float a, float b, float c, float d, int i) {
    float r = a;
    r = (i == 1) ? b : r;
    r = (i == 2) ? c : r;
    r = (i == 3) ? d : r;
    return r;
}

__global__ __launch_bounds__(256) void ps1d_shfl_kernel(
    const float4* __restrict__ x4, float4* __restrict__ out4) {
    int t = blockIdx.x * 256 + threadIdx.x;   // < 2^23, fits in int
    int p      = t & 3;            // which source row within the group
    int grp    = t >> 2;           // global group id
    int lchunk = grp & (LQ - 1);   // float4 chunk within a row
    int bc     = grp >> 12;        // grp / 4096 : which (b, c')

    // load: row p of this bc, chunk lchunk.  float4 index:
    //   bc*16384 + p*4096 + lchunk
    float4 v = x4[(bc << 14) + (p << 12) + lchunk];

    int lane  = threadIdx.x & 63;
    int gbase = lane & ~3;

    // transpose rounds (r = 0..3): got_r = v_{(p+r)&3}[p]
    float g0 = sel4(v, p);
    float g1 = __shfl(sel4(v, (p + 3) & 3), gbase | ((p + 1) & 3), 64);
    float g2 = __shfl(sel4(v, (p + 2) & 3), gbase | ((p + 2) & 3), 64);
    float g3 = __shfl(sel4(v, (p + 1) & 3), gbase | ((p + 3) & 3), 64);

    // w[j] = got_{(j-p)&3}
    float4 w;
    w.x = selg(g0, g1, g2, g3, (4 - p) & 3);
    w.y = selg(g0, g1, g2, g3, (5 - p) & 3);
    w.z = selg(g0, g1, g2, g3, (6 - p) & 3);
    w.w = selg(g0, g1, g2, g3, (7 - p) & 3);

    out4[t] = w;   // out quad index == t (grp*4 + p), fully coalesced
}

extern "C" void kernel_launch(void* const* d_in, const int* in_sizes, int n_in,
                              void* d_out, int out_size, void* d_ws, size_t ws_size,
                              hipStream_t stream) {
    const float4* x4 = (const float4*)d_in[0];
    float4* out4 = (float4*)d_out;

    const int block = 256;
    const int grid = TOTAL / block;   // 32768 blocks
    ps1d_shfl_kernel<<<grid, block, 0, stream>>>(x4, out4);
}